// Round 5
// baseline (33.603 us; speedup 1.0000x reference)
//
#include <hip/hip_runtime.h>
#include <math.h>

static constexpr int   B    = 256;   // batch
static constexpr int   D    = 256;   // feature dim
static constexpr int   NSV  = 512;   // P == Q
static constexpr int   RG   = 16;    // SV row-groups
static constexpr int   RPS  = NSV / RG;   // 32 rows per set per block
static constexpr int   RPB  = 2 * RPS;    // 64 tile rows (set1 then set0)
static constexpr int   NB   = 8;          // batches per block (2 waves x 4)
static constexpr int   NT   = 128;        // 2 waves
static constexpr int   KC   = 64;         // chunk (floats per row)
static constexpr int   SPR  = KC / 4;     // 16 f4 slots per row
static constexpr int   NBLK = RG * (B / NB);  // 512 blocks
static constexpr float G    = 0.1f;
static constexpr float CSH  = 26.0f;      // fixed LSE shift; cancels in LSE0-LSE1

typedef float f32x2 __attribute__((ext_vector_type(2)));

__device__ __forceinline__ void gld16(const void* g, void* l) {
    __builtin_amdgcn_global_load_lds((__attribute__((address_space(1))) void*)g,
                                     (__attribute__((address_space(3))) void*)l,
                                     16, 0, 0);
}

__global__ __launch_bounds__(NT)
void k_fused(const float* __restrict__ x,
             const float* __restrict__ sv1,
             const float* __restrict__ sv0,
             const float* __restrict__ a1,
             const float* __restrict__ a0,
             float* __restrict__ S,        // ws: S[2*B] accumulators
             unsigned* __restrict__ cnt,   // ws: arrival counter
             float* __restrict__ out)
{
    __shared__ float tile[2][RPB * KC];   // 2 x 16 KiB SV chunk buffers

    const int t     = threadIdx.x;
    const int rg    = blockIdx.x;
    const int bbase = blockIdx.y * NB;
    const int r     = t & (RPB - 1);      // tile row owned by this thread
    // wave-uniform batch-group -> x addresses become SGPR (scalar loads)
    const int bgu   = __builtin_amdgcn_readfirstlane(t >> 6);
    const float* xw = x + (size_t)(bbase + bgu * 4) * D;

    // SV chunk staging: linear LDS dest, XOR-swizzled global source (involution)
    auto stage = [&](int c, int buf) {
        #pragma unroll
        for (int i = 0; i < (RPB * SPR) / NT; ++i) {   // 8 slots/thread
            const int f  = i * NT + t;
            const int rr = f >> 4;          // tile row
            const int p  = f & 15;          // physical f4 slot
            const int q  = p ^ (rr & 7);    // logical slot
            const float* src = (rr < RPS)
                ? (sv1 + (size_t)(rg * RPS + rr) * D)
                : (sv0 + (size_t)(rg * RPS + (rr - RPS)) * D);
            gld16(src + c * KC + q * 4, &tile[buf][f * 4]);
        }
    };

    f32x2 ssq = {0.f, 0.f};
    f32x2 d0 = {0.f, 0.f}, d1 = {0.f, 0.f}, d2 = {0.f, 0.f}, d3 = {0.f, 0.f};

    auto compute = [&](int cc, int buf) {
        const float4* tf = reinterpret_cast<const float4*>(&tile[buf][0]);
        const float*  xc = xw + cc * KC;
        #pragma unroll 4
        for (int kk = 0; kk < SPR; ++kk) {
            const int p = kk ^ (r & 7);                 // de-swizzle
            const float4 s4 = tf[(r << 4) + p];
            const f32x2 sa = {s4.x, s4.y};
            const f32x2 sb = {s4.z, s4.w};
            const float4 x0 = *reinterpret_cast<const float4*>(xc + 0 * D + kk * 4);
            const float4 x1 = *reinterpret_cast<const float4*>(xc + 1 * D + kk * 4);
            const float4 x2 = *reinterpret_cast<const float4*>(xc + 2 * D + kk * 4);
            const float4 x3 = *reinterpret_cast<const float4*>(xc + 3 * D + kk * 4);
            ssq = __builtin_elementwise_fma(sa, sa, ssq);
            ssq = __builtin_elementwise_fma(sb, sb, ssq);
            d0 = __builtin_elementwise_fma(sa, (f32x2){x0.x, x0.y}, d0);
            d0 = __builtin_elementwise_fma(sb, (f32x2){x0.z, x0.w}, d0);
            d1 = __builtin_elementwise_fma(sa, (f32x2){x1.x, x1.y}, d1);
            d1 = __builtin_elementwise_fma(sb, (f32x2){x1.z, x1.w}, d1);
            d2 = __builtin_elementwise_fma(sa, (f32x2){x2.x, x2.y}, d2);
            d2 = __builtin_elementwise_fma(sb, (f32x2){x2.z, x2.w}, d2);
            d3 = __builtin_elementwise_fma(sa, (f32x2){x3.x, x3.y}, d3);
            d3 = __builtin_elementwise_fma(sb, (f32x2){x3.z, x3.w}, d3);
        }
    };

    // depth-2 prefetch pipeline over 4 chunks, counted vmcnt
    stage(0, 0);
    stage(1, 1);

    asm volatile("s_waitcnt vmcnt(8)" ::: "memory");   // c0 done
    __builtin_amdgcn_s_barrier();
    __builtin_amdgcn_sched_barrier(0);
    compute(0, 0);
    __builtin_amdgcn_sched_barrier(0);
    __builtin_amdgcn_s_barrier();                      // both waves done with buf0
    stage(2, 0);

    asm volatile("s_waitcnt vmcnt(8)" ::: "memory");   // c1 done
    __builtin_amdgcn_s_barrier();
    __builtin_amdgcn_sched_barrier(0);
    compute(1, 1);
    __builtin_amdgcn_sched_barrier(0);
    __builtin_amdgcn_s_barrier();                      // both waves done with buf1
    stage(3, 1);

    asm volatile("s_waitcnt vmcnt(8)" ::: "memory");   // c2 done
    __builtin_amdgcn_s_barrier();
    __builtin_amdgcn_sched_barrier(0);
    compute(2, 0);

    asm volatile("s_waitcnt vmcnt(0)" ::: "memory");   // c3 done
    __builtin_amdgcn_s_barrier();
    __builtin_amdgcn_sched_barrier(0);
    compute(3, 1);

    // ---- epilogue: score -> exp -> per-set 32-lane reduction ----
    const int   rloc = r & (RPS - 1);
    const int   set  = r >> 5;            // 0 = sv1 rows, 1 = sv0 rows
    const float av   = set ? a0[rg * RPS + rloc] : a1[rg * RPS + rloc];
    const float lal  = __logf(av);
    const float sq   = ssq.x + ssq.y;

    float e0 = __expf(G * (sq - 2.f * (d0.x + d0.y)) - lal - CSH);
    float e1 = __expf(G * (sq - 2.f * (d1.x + d1.y)) - lal - CSH);
    float e2 = __expf(G * (sq - 2.f * (d2.x + d2.y)) - lal - CSH);
    float e3 = __expf(G * (sq - 2.f * (d3.x + d3.y)) - lal - CSH);

    #pragma unroll
    for (int off = 16; off > 0; off >>= 1) {   // reduce within 32-lane halves
        e0 += __shfl_xor(e0, off);
        e1 += __shfl_xor(e1, off);
        e2 += __shfl_xor(e2, off);
        e3 += __shfl_xor(e3, off);
    }
    const int l  = t & 63;
    const int bg = t >> 6;
    if (l == 0 || l == 32) {
        float* dst = S + set * B + bbase + bg * 4;
        atomicAdd(&dst[0], e0);
        atomicAdd(&dst[1], e1);
        atomicAdd(&dst[2], e2);
        atomicAdd(&dst[3], e3);
    }

    // ---- last block finalizes out[b] = log(S0) - log(S1) ----
    __shared__ int lastflag;
    __syncthreads();
    __threadfence();                       // release our data-atomics device-wide
    if (t == 0) {
        const unsigned old = atomicAdd(cnt, 1u);
        lastflag = (old == (unsigned)(NBLK - 1));
    }
    __syncthreads();
    if (lastflag) {
        #pragma unroll
        for (int i = t; i < B; i += NT) {  // 2 iterations
            const float s1 = __hip_atomic_load(&S[i],     __ATOMIC_RELAXED, __HIP_MEMORY_SCOPE_AGENT);
            const float s0 = __hip_atomic_load(&S[B + i], __ATOMIC_RELAXED, __HIP_MEMORY_SCOPE_AGENT);
            out[i] = __logf(s0) - __logf(s1);
        }
    }
}

extern "C" void kernel_launch(void* const* d_in, const int* in_sizes, int n_in,
                              void* d_out, int out_size, void* d_ws, size_t ws_size,
                              hipStream_t stream) {
    const float* x   = (const float*)d_in[0];
    const float* sv1 = (const float*)d_in[1];
    const float* sv0 = (const float*)d_in[2];
    const float* a1  = (const float*)d_in[3];
    const float* a0  = (const float*)d_in[4];
    float*    S   = (float*)d_ws;
    unsigned* cnt = (unsigned*)(S + 2 * B);
    float*    out = (float*)d_out;

    // zero accumulators + arrival counter (capture-legal async memset node)
    hipMemsetAsync(d_ws, 0, (2 * B + 1) * sizeof(float), stream);

    dim3 g1(RG, B / NB);   // 16 x 32 = 512 blocks
    k_fused<<<g1, NT, 0, stream>>>(x, sv1, sv0, a1, a0, S, cnt, out);
}

// Round 6
// 30.281 us; speedup vs baseline: 1.1097x; 1.1097x over previous
//
#include <hip/hip_runtime.h>
#include <math.h>

static constexpr int   B    = 256;   // batch
static constexpr int   D    = 256;   // feature dim
static constexpr int   NSV  = 512;   // P == Q
static constexpr int   NB   = 4;     // batches per block
static constexpr int   NBLK = B / NB;     // 64 blocks
static constexpr int   NT   = 256;        // threads (4 waves)
static constexpr int   PR   = 256;        // panel rows (== NT, 1 row/thread)
static constexpr int   NP   = 2 * NSV / PR;  // 4 panels (0,1 = sv1; 2,3 = sv0)
static constexpr int   KC   = 64;         // chunk floats per row
static constexpr int   SPR  = KC / 4;     // 16 f4 slots per row
static constexpr int   NCH  = D / KC;     // 4 chunks
static constexpr int   NS   = NP * NCH;   // 16 stages
static constexpr float G    = 0.1f;
static constexpr float CSH  = 26.0f;      // fixed LSE shift; cancels in LSE0-LSE1

typedef float f32x2 __attribute__((ext_vector_type(2)));

__device__ __forceinline__ void gld16(const void* g, void* l) {
    __builtin_amdgcn_global_load_lds((__attribute__((address_space(1))) void*)g,
                                     (__attribute__((address_space(3))) void*)l,
                                     16, 0, 0);
}

__global__ __launch_bounds__(NT)
void k_all(const float* __restrict__ x,
           const float* __restrict__ sv1,
           const float* __restrict__ sv0,
           const float* __restrict__ a1,
           const float* __restrict__ a0,
           float* __restrict__ out)
{
    __shared__ float tile[2][PR * KC];   // 2 x 64 KiB double buffer
    __shared__ float red[32];

    const int t     = threadIdx.x;
    const int bbase = blockIdx.x * NB;
    const float* xw = x + (size_t)bbase * D;   // block-uniform -> scalar loads

    // alpha prefetch (4 vector loads, oldest in vmcnt queue; drained by first wait)
    const float av0 = a1[t];
    const float av1 = a1[PR + t];
    const float av2 = a0[t];
    const float av3 = a0[PR + t];
    __builtin_amdgcn_sched_barrier(0);

    // stage s: panel pn = s>>2, chunk c = s&3, buffer s&1.
    // linear LDS dest, XOR-swizzled global source (involution q = p ^ (row&7))
    auto stage = [&](int s) {
        const int pn = s >> 2, c = s & 3, buf = s & 1;
        #pragma unroll
        for (int i = 0; i < (PR * SPR) / NT; ++i) {   // 16 slots/thread
            const int f  = i * NT + t;
            const int rr = f >> 4;          // tile row 0..255
            const int p  = f & 15;          // physical f4 slot
            const int q  = p ^ (rr & 7);    // logical slot
            const int gr = pn * PR + rr;    // global row 0..1023
            const float* src = (gr < NSV)
                ? (sv1 + (size_t)gr * D)
                : (sv0 + (size_t)(gr - NSV) * D);
            gld16(src + c * KC + q * 4, &tile[buf][f * 4]);
        }
    };

    f32x2 ssq = {0.f, 0.f};
    f32x2 d0 = {0.f, 0.f}, d1 = {0.f, 0.f}, d2 = {0.f, 0.f}, d3 = {0.f, 0.f};
    float es10 = 0.f, es11 = 0.f, es12 = 0.f, es13 = 0.f;   // set1 running sums
    float es00 = 0.f, es01 = 0.f, es02 = 0.f, es03 = 0.f;   // set0 running sums

    auto compute = [&](int s) {
        const int c = s & 3, buf = s & 1;
        const float4* tf = reinterpret_cast<const float4*>(&tile[buf][0]);
        const float*  xc = xw + c * KC;
        #pragma unroll 4
        for (int kk = 0; kk < SPR; ++kk) {
            const int p = kk ^ (t & 7);                 // de-swizzle
            const float4 s4 = tf[(t << 4) + p];
            const f32x2 sa = {s4.x, s4.y};
            const f32x2 sb = {s4.z, s4.w};
            const float4 x0 = *reinterpret_cast<const float4*>(xc + 0 * D + kk * 4);
            const float4 x1 = *reinterpret_cast<const float4*>(xc + 1 * D + kk * 4);
            const float4 x2 = *reinterpret_cast<const float4*>(xc + 2 * D + kk * 4);
            const float4 x3 = *reinterpret_cast<const float4*>(xc + 3 * D + kk * 4);
            ssq = __builtin_elementwise_fma(sa, sa, ssq);
            ssq = __builtin_elementwise_fma(sb, sb, ssq);
            d0 = __builtin_elementwise_fma(sa, (f32x2){x0.x, x0.y}, d0);
            d0 = __builtin_elementwise_fma(sb, (f32x2){x0.z, x0.w}, d0);
            d1 = __builtin_elementwise_fma(sa, (f32x2){x1.x, x1.y}, d1);
            d1 = __builtin_elementwise_fma(sb, (f32x2){x1.z, x1.w}, d1);
            d2 = __builtin_elementwise_fma(sa, (f32x2){x2.x, x2.y}, d2);
            d2 = __builtin_elementwise_fma(sb, (f32x2){x2.z, x2.w}, d2);
            d3 = __builtin_elementwise_fma(sa, (f32x2){x3.x, x3.y}, d3);
            d3 = __builtin_elementwise_fma(sb, (f32x2){x3.z, x3.w}, d3);
        }
    };

    // prologue: depth-2 prefetch
    stage(0);
    __builtin_amdgcn_sched_barrier(0);
    stage(1);

    #pragma unroll
    for (int s = 0; s < NS; ++s) {
        if (s < NS - 1) asm volatile("s_waitcnt vmcnt(16)" ::: "memory");
        else            asm volatile("s_waitcnt vmcnt(0)"  ::: "memory");
        __builtin_amdgcn_s_barrier();
        __builtin_amdgcn_sched_barrier(0);
        compute(s);
        if ((s & 3) == 3) {
            // panel finished: fold row into running exp-sums
            const int pn = s >> 2;
            const float lal = __logf(pn == 0 ? av0 : pn == 1 ? av1 : pn == 2 ? av2 : av3);
            const float sq  = ssq.x + ssq.y;
            const float e0 = __expf(G * (sq - 2.f * (d0.x + d0.y)) - lal - CSH);
            const float e1 = __expf(G * (sq - 2.f * (d1.x + d1.y)) - lal - CSH);
            const float e2 = __expf(G * (sq - 2.f * (d2.x + d2.y)) - lal - CSH);
            const float e3 = __expf(G * (sq - 2.f * (d3.x + d3.y)) - lal - CSH);
            if (pn < 2) { es10 += e0; es11 += e1; es12 += e2; es13 += e3; }
            else        { es00 += e0; es01 += e1; es02 += e2; es03 += e3; }
            ssq = (f32x2){0.f, 0.f};
            d0 = (f32x2){0.f, 0.f}; d1 = (f32x2){0.f, 0.f};
            d2 = (f32x2){0.f, 0.f}; d3 = (f32x2){0.f, 0.f};
        }
        __builtin_amdgcn_sched_barrier(0);
        __builtin_amdgcn_s_barrier();
        if (s < NS - 2) stage(s + 2);
    }

    // ---- block reduction of 8 running sums ----
    #pragma unroll
    for (int off = 32; off > 0; off >>= 1) {
        es10 += __shfl_xor(es10, off); es11 += __shfl_xor(es11, off);
        es12 += __shfl_xor(es12, off); es13 += __shfl_xor(es13, off);
        es00 += __shfl_xor(es00, off); es01 += __shfl_xor(es01, off);
        es02 += __shfl_xor(es02, off); es03 += __shfl_xor(es03, off);
    }
    const int wv = t >> 6;
    if ((t & 63) == 0) {
        float* w = red + wv * 8;
        w[0] = es10; w[1] = es11; w[2] = es12; w[3] = es13;
        w[4] = es00; w[5] = es01; w[6] = es02; w[7] = es03;
    }
    __syncthreads();
    if (t < NB) {
        const float s1 = red[t] + red[8 + t] + red[16 + t] + red[24 + t];
        const float s0 = red[4 + t] + red[12 + t] + red[20 + t] + red[28 + t];
        out[bbase + t] = __logf(s0) - __logf(s1);   // CSH cancels
    }
}

extern "C" void kernel_launch(void* const* d_in, const int* in_sizes, int n_in,
                              void* d_out, int out_size, void* d_ws, size_t ws_size,
                              hipStream_t stream) {
    const float* x   = (const float*)d_in[0];
    const float* sv1 = (const float*)d_in[1];
    const float* sv0 = (const float*)d_in[2];
    const float* a1  = (const float*)d_in[3];
    const float* a0  = (const float*)d_in[4];
    float* out = (float*)d_out;

    k_all<<<NBLK, NT, 0, stream>>>(x, sv1, sv0, a1, a0, out);
}

// Round 7
// 13.776 us; speedup vs baseline: 2.4392x; 2.1981x over previous
//
#include <hip/hip_runtime.h>
#include <math.h>

static constexpr int   B    = 256;   // batch
static constexpr int   D    = 256;   // feature dim
static constexpr int   NSV  = 512;   // P == Q
static constexpr int   RG   = 16;    // SV row-group slices
static constexpr int   RPS  = NSV / RG;   // 32 rows per set per block
static constexpr int   RPB  = 2 * RPS;    // 64 tile rows (set1 then set0)
static constexpr int   NB   = 4;          // batches per block
static constexpr int   NT   = 64;         // ONE wave per block -> no barriers
static constexpr int   KC   = 64;         // chunk floats per row
static constexpr int   SPR  = KC / 4;     // 16 f4 slots per row
static constexpr float G    = 0.1f;
static constexpr float CSH  = 26.0f;      // fixed LSE shift; cancels in LSE0-LSE1

typedef float f32x2 __attribute__((ext_vector_type(2)));

__device__ __forceinline__ void gld16(const void* g, void* l) {
    __builtin_amdgcn_global_load_lds((__attribute__((address_space(1))) void*)g,
                                     (__attribute__((address_space(3))) void*)l,
                                     16, 0, 0);
}

__global__ __launch_bounds__(NT)
void k_all(const float* __restrict__ x,
           const float* __restrict__ sv1,
           const float* __restrict__ sv0,
           const float* __restrict__ a1,
           const float* __restrict__ a0,
           float* __restrict__ ws)
{
    __shared__ float tile[2][RPB * KC];   // 2 x 16 KiB SV chunk buffers
    __shared__ float xls[NB * D];         // 4 KiB x rows (read as broadcasts)

    const int t     = threadIdx.x;        // == lane; == tile row
    const int rg    = blockIdx.x;
    const int bbase = blockIdx.y * NB;

    // ---- stage x rows once (linear, vmcnt slots 0..3) ----
    {
        const float* xsrc = x + (size_t)bbase * D;
        #pragma unroll
        for (int i = 0; i < (NB * D / 4) / NT; ++i) {   // 4 slots/lane
            const int f = i * NT + t;
            gld16(xsrc + f * 4, &xls[f * 4]);
        }
    }

    // SV chunk staging: linear LDS dest, XOR-swizzled global source (involution)
    auto stage = [&](int c, int buf) {
        #pragma unroll
        for (int i = 0; i < (RPB * SPR) / NT; ++i) {   // 16 slots/lane
            const int f  = i * NT + t;
            const int rr = f >> 4;          // tile row 0..63
            const int p  = f & 15;          // physical f4 slot
            const int q  = p ^ (rr & 7);    // logical slot
            const float* src = (rr < RPS)
                ? (sv1 + (size_t)(rg * RPS + rr) * D)
                : (sv0 + (size_t)(rg * RPS + (rr - RPS)) * D);
            gld16(src + c * KC + q * 4, &tile[buf][f * 4]);
        }
    };

    f32x2 ssq = {0.f, 0.f};
    f32x2 d0 = {0.f, 0.f}, d1 = {0.f, 0.f}, d2 = {0.f, 0.f}, d3 = {0.f, 0.f};

    auto compute = [&](int cc, int buf) {
        const float4* tf = reinterpret_cast<const float4*>(&tile[buf][0]);
        const float4* xf = reinterpret_cast<const float4*>(xls) + cc * SPR;
        #pragma unroll 4
        for (int kk = 0; kk < SPR; ++kk) {
            const int p = kk ^ (t & 7);                 // de-swizzle
            const float4 s4 = tf[(t << 4) + p];
            const f32x2 sa = {s4.x, s4.y};
            const f32x2 sb = {s4.z, s4.w};
            const float4 x0 = xf[0 * (D / 4) + kk];     // broadcast ds_read_b128
            const float4 x1 = xf[1 * (D / 4) + kk];
            const float4 x2 = xf[2 * (D / 4) + kk];
            const float4 x3 = xf[3 * (D / 4) + kk];
            ssq = __builtin_elementwise_fma(sa, sa, ssq);
            ssq = __builtin_elementwise_fma(sb, sb, ssq);
            d0 = __builtin_elementwise_fma(sa, (f32x2){x0.x, x0.y}, d0);
            d0 = __builtin_elementwise_fma(sb, (f32x2){x0.z, x0.w}, d0);
            d1 = __builtin_elementwise_fma(sa, (f32x2){x1.x, x1.y}, d1);
            d1 = __builtin_elementwise_fma(sb, (f32x2){x1.z, x1.w}, d1);
            d2 = __builtin_elementwise_fma(sa, (f32x2){x2.x, x2.y}, d2);
            d2 = __builtin_elementwise_fma(sb, (f32x2){x2.z, x2.w}, d2);
            d3 = __builtin_elementwise_fma(sa, (f32x2){x3.x, x3.y}, d3);
            d3 = __builtin_elementwise_fma(sb, (f32x2){x3.z, x3.w}, d3);
        }
        // all ds_reads of this buffer consumed before next gld16 targets it
        asm volatile("s_waitcnt lgkmcnt(0)" ::: "memory");
        __builtin_amdgcn_sched_barrier(0);
    };

    // barrier-free counted-vmcnt pipeline (single wave owns the whole block)
    stage(0, 0);
    stage(1, 1);

    asm volatile("s_waitcnt vmcnt(16)" ::: "memory");  // x + c0 done
    __builtin_amdgcn_sched_barrier(0);
    compute(0, 0);
    stage(2, 0);

    asm volatile("s_waitcnt vmcnt(16)" ::: "memory");  // c1 done
    __builtin_amdgcn_sched_barrier(0);
    compute(1, 1);
    stage(3, 1);

    asm volatile("s_waitcnt vmcnt(16)" ::: "memory");  // c2 done
    __builtin_amdgcn_sched_barrier(0);
    compute(2, 0);

    asm volatile("s_waitcnt vmcnt(0)" ::: "memory");   // c3 done
    __builtin_amdgcn_sched_barrier(0);
    compute(3, 1);

    // ---- epilogue: score -> exp -> 32-lane reduce per set ----
    const int   rloc = t & (RPS - 1);
    const int   set  = t >> 5;            // 0 = sv1 rows, 1 = sv0 rows
    const float av   = set ? a0[rg * RPS + rloc] : a1[rg * RPS + rloc];
    const float lal  = __logf(av);
    const float sq   = ssq.x + ssq.y;

    float e0 = __expf(G * (sq - 2.f * (d0.x + d0.y)) - lal - CSH);
    float e1 = __expf(G * (sq - 2.f * (d1.x + d1.y)) - lal - CSH);
    float e2 = __expf(G * (sq - 2.f * (d2.x + d2.y)) - lal - CSH);
    float e3 = __expf(G * (sq - 2.f * (d3.x + d3.y)) - lal - CSH);

    #pragma unroll
    for (int off = 16; off > 0; off >>= 1) {   // reduce within 32-lane halves
        e0 += __shfl_xor(e0, off);
        e1 += __shfl_xor(e1, off);
        e2 += __shfl_xor(e2, off);
        e3 += __shfl_xor(e3, off);
    }
    if (t == 0 || t == 32) {
        float* dst = ws + (size_t)set * (RG * B) + rg * B + bbase;
        dst[0] = e0; dst[1] = e1; dst[2] = e2; dst[3] = e3;
    }
}

// out[b] = log(S0) - log(S1); the CSH shift cancels exactly.
__global__ __launch_bounds__(B)
void k_final(const float* __restrict__ ws, float* __restrict__ out)
{
    const int b = threadIdx.x;
    float S1 = 0.f, S0 = 0.f;
    #pragma unroll
    for (int rg = 0; rg < RG; ++rg) {
        S1 += ws[rg * B + b];
        S0 += ws[RG * B + rg * B + b];
    }
    out[b] = __logf(S0) - __logf(S1);
}

extern "C" void kernel_launch(void* const* d_in, const int* in_sizes, int n_in,
                              void* d_out, int out_size, void* d_ws, size_t ws_size,
                              hipStream_t stream) {
    const float* x   = (const float*)d_in[0];
    const float* sv1 = (const float*)d_in[1];
    const float* sv0 = (const float*)d_in[2];
    const float* a1  = (const float*)d_in[3];
    const float* a0  = (const float*)d_in[4];
    float* ws  = (float*)d_ws;
    float* out = (float*)d_out;

    dim3 g1(RG, B / NB);   // 16 x 64 = 1024 single-wave blocks
    k_all<<<g1, NT, 0, stream>>>(x, sv1, sv0, a1, a0, ws);
    k_final<<<1, B, 0, stream>>>(ws, out);
}